// Round 10
// baseline (208.337 us; speedup 1.0000x reference)
//
#include <hip/hip_runtime.h>
#include <stdint.h>

// BinConv2d: sign(x) conv3x3(pad1) sign(w) + batch-stat BN.
// Conv as int8 implicit GEMM on MFMA (v_mfma_i32_32x32x32_i8), integer-exact.
// R10: wave = 64px x 64oc (acc[2][2], 4 indep chains), A + B both from LDS
// (conflict-free k-outer layouts), B double-buffered via reg-staged global loads
// (one barrier/tap), stats fused in-kernel (butterfly + LDS i32 + atomic flush).

#define HH 56
#define WW 56
#define CC 128
#define OO 128
#define NIMG 64
#define PIX (HH*WW)               // 3136
#define CNT (NIMG*PIX)            // 200704 per channel
#define TOT ((size_t)NIMG*OO*PIX) // 25690112

typedef int v4i  __attribute__((ext_vector_type(4)));
typedef int v16i __attribute__((ext_vector_type(16)));

// ws layout (bytes)
#define WS_WBT   0                 // 9*8*128*16 int8 (wbt2[tap][kc][o][16]) = 147456
#define WS_STATS 147456            // 128*{i64 sum, i64 sq} = 2048
#define WS_SS    149504            // float2[128] = 1024
#define WS_XI8   151552            // NHWC int8 sign(x): 64*3136*128 -> ends 25841664
#define WS_Y16   25841664          // TOT*int16 = 51380224 -> ends 77221888
#define WS_NEED  (25841664ULL + (size_t)TOT * 2)

// wbt2[tap][kc][o] x 16B: k-outer; B loads lane-consecutive 16B (coalesced + LDS-friendly)
__global__ void pack_w_i8(const float* __restrict__ w, char* __restrict__ wbt) {
    int t = blockIdx.x * 256 + threadIdx.x;
    if (t >= 1152) return;
    int tap = t >> 7, o = t & 127;
    const float* wp = w + (size_t)o * (CC * 9) + tap;   // OIHW: + c*9
    #pragma unroll
    for (int kc = 0; kc < 8; ++kc) {
        v4i v;
        #pragma unroll
        for (int wd = 0; wd < 4; ++wd) {
            unsigned u = 0;
            #pragma unroll
            for (int b = 0; b < 4; ++b) {
                int c = kc * 16 + wd * 4 + b;
                float f = wp[c * 9];
                int s = (f > 0.f) - (f < 0.f);
                u |= (unsigned)((unsigned char)(char)s) << (8 * b);
            }
            v[wd] = (int)u;
        }
        *(v4i*)(wbt + (((size_t)tap * 8 + kc) * 128 + o) * 16) = v;
    }
}

// xi8[n][h][w][c] int8 (NHWC, c contiguous = MFMA K dim)
__global__ void pack_x_i8(const float* __restrict__ x, char* __restrict__ xi8) {
    int n = blockIdx.y;
    int p = blockIdx.x * 256 + threadIdx.x;
    if (p >= PIX) return;
    const float* xp = x + (size_t)n * CC * PIX + p;
    char* dst = xi8 + ((size_t)n * PIX + p) * CC;
    #pragma unroll
    for (int chunk = 0; chunk < 8; ++chunk) {
        v4i v;
        #pragma unroll
        for (int wd = 0; wd < 4; ++wd) {
            unsigned u = 0;
            #pragma unroll
            for (int b = 0; b < 4; ++b) {
                int c = chunk * 16 + wd * 4 + b;
                float f = xp[(size_t)c * PIX];
                int s = (f > 0.f) - (f < 0.f);
                u |= (unsigned)((unsigned char)(char)s) << (8 * b);
            }
            v[wd] = (int)u;
        }
        *(v4i*)(dst + chunk * 16) = v;
    }
}

// MODE 1: y16 out. MODE 2: float y to out (fallback; normf then runs in-place).
// Block 256 = 4 waves (2 px-halves x 2 oc-halves); block tile = 128 px x 128 oc.
// Wave tile = 64 px (2 mt) x 64 oc (2 nt), acc[2][2] = 64 AGPR.
// Atile: 6 rows x 58 cols, k-outer [kc][slot]16B (R9-verified mapping).
// Bt: per-tap 16KB double-buffered, reg-staged from global (T14), 1 barrier/tap.
// MFMA: D = mfma(A=weights, B=activations) -> D col = px (ln31), row = oc-offset.
template <int MODE>
__global__ __launch_bounds__(256, 2) void conv_mfma(
    const char* __restrict__ xi8, const char* __restrict__ wbt,
    unsigned long long* stats,
    short* __restrict__ y16, float* __restrict__ out)
{
    __shared__ __align__(16) char Atile[8 * 348 * 16];   // 44544
    __shared__ __align__(16) char Bt[2][16384];          // 32768
    __shared__ int sstat[256];                           // 128 ch x {sum, sq} i32

    const int strip = blockIdx.x;   // 0..24, 128 px each (last: 64 valid)
    const int n = blockIdx.y;
    const int tid = threadIdx.x;
    const int lane = tid & 63;
    const int wave = tid >> 6;
    const int wm = wave & 1;        // px half
    const int wn = wave >> 1;       // oc half
    const int ln31 = lane & 31;
    const int kbase = lane >> 5;    // k half (0/1)
    const int p0 = strip * 128;
    const int r0 = p0 / 56 - 1;     // first tile image-row (may be -1)

    // ---- stage A (6 rows x 58 cols, zero halo/OOB), k-outer
    {
        const char* xim = xi8 + (size_t)n * PIX * CC;
        for (int idx = tid; idx < 8 * 348; idx += 256) {
            int kc = idx / 348, p = idx - kc * 348;
            int pr = p / 58, pc = p - pr * 58;
            int gr = r0 + pr, gw = pc - 1;
            v4i v = {0, 0, 0, 0};
            if (gr >= 0 && gr < HH && gw >= 0 && gw < WW)
                v = *(const v4i*)(xim + ((size_t)(gr * WW + gw)) * CC + kc * 16);
            *(v4i*)(Atile + idx * 16) = v;
        }
    }
    // ---- stage B tap 0 (reg-staged) + zero stats LDS
    {
        const char* gs = wbt + tid * 16;
        v4i s0 = *(const v4i*)(gs);
        v4i s1 = *(const v4i*)(gs + 4096);
        v4i s2 = *(const v4i*)(gs + 8192);
        v4i s3 = *(const v4i*)(gs + 12288);
        char* ds = Bt[0] + tid * 16;
        *(v4i*)(ds) = s0; *(v4i*)(ds + 4096) = s1;
        *(v4i*)(ds + 8192) = s2; *(v4i*)(ds + 12288) = s3;
        sstat[tid] = 0;
    }

    // per-mt activation base: pixel q = p0 + wm*64 + mt*32 + ln31
    int xpb[2];
    #pragma unroll
    for (int mt = 0; mt < 2; ++mt) {
        int q = p0 + wm * 64 + mt * 32 + ln31;
        int qr = q / 56;
        int hl0 = qr - (r0 + 1);               // 0..3
        int wwp = q - qr * 56;
        xpb[mt] = (hl0 * 58 + wwp) * 16 + kbase * 5568;   // + (dr*58+dc)*16 + ks*2*5568
    }
    // weight-frag base in Bt: ((kc)*128 + o)*16, o = wn*64 + nt*32 + ln31, kc = ks*2+kbase
    const int wofs = (kbase * 128 + wn * 64 + ln31) * 16;  // + nt*512 + ks*4096

    v16i acc[2][2];
    #pragma unroll
    for (int mt = 0; mt < 2; ++mt)
        #pragma unroll
        for (int nt = 0; nt < 2; ++nt)
            #pragma unroll
            for (int i = 0; i < 16; ++i) acc[mt][nt][i] = 0;

    __syncthreads();

    int cur = 0;
    #pragma unroll 1
    for (int tap = 0; tap < 9; ++tap) {
        // issue next tap's B loads early (hidden under this tap's ds_reads + MFMAs)
        v4i s0, s1, s2, s3;
        if (tap < 8) {
            const char* gs = wbt + (size_t)(tap + 1) * 16384 + tid * 16;
            s0 = *(const v4i*)(gs);
            s1 = *(const v4i*)(gs + 4096);
            s2 = *(const v4i*)(gs + 8192);
            s3 = *(const v4i*)(gs + 12288);
        }
        const int tapr = tap / 3, tapc = tap - tapr * 3;
        const int dtap = (tapr * 58 + tapc) * 16;

        const char* B0 = Bt[cur];
        v4i wf[2][4];   // [nt][ks] weights (A-operand)
        #pragma unroll
        for (int nt = 0; nt < 2; ++nt)
            #pragma unroll
            for (int ks = 0; ks < 4; ++ks)
                wf[nt][ks] = *(const v4i*)(B0 + wofs + nt * 512 + ks * 4096);
        v4i xf[2][4];   // [mt][ks] activations (B-operand)
        #pragma unroll
        for (int mt = 0; mt < 2; ++mt)
            #pragma unroll
            for (int ks = 0; ks < 4; ++ks)
                xf[mt][ks] = *(const v4i*)(Atile + xpb[mt] + dtap + ks * 2 * 5568);

        #pragma unroll
        for (int ks = 0; ks < 4; ++ks)
            #pragma unroll
            for (int mt = 0; mt < 2; ++mt)
                #pragma unroll
                for (int nt = 0; nt < 2; ++nt)
                    acc[mt][nt] = __builtin_amdgcn_mfma_i32_32x32x32_i8(
                        wf[nt][ks], xf[mt][ks], acc[mt][nt], 0, 0, 0);

        if (tap < 8) {   // write staged B into idle buffer (safe: other buf, post-prev-barrier)
            char* ds = Bt[cur ^ 1] + tid * 16;
            *(v4i*)(ds) = s0; *(v4i*)(ds + 4096) = s1;
            *(v4i*)(ds + 8192) = s2; *(v4i*)(ds + 12288) = s3;
        }
        __syncthreads();
        cur ^= 1;
    }

    // ---- stats: butterfly over px lanes, accumulate per-channel into LDS (i32-safe:
    // |sum|<=64*1152=73K, sq<=64*1152^2=85M per block-channel)
    #pragma unroll
    for (int nt = 0; nt < 2; ++nt) {
        #pragma unroll
        for (int r = 0; r < 16; ++r) {
            int a = acc[0][nt][r], b = acc[1][nt][r];
            int s = a + b;
            int q2 = a * a + b * b;
            #pragma unroll
            for (int m = 1; m <= 16; m <<= 1) {
                s += __shfl_xor(s, m);
                q2 += __shfl_xor(q2, m);
            }
            if (ln31 == 0) {
                int ch = wn * 64 + nt * 32 + (r & 3) + 8 * (r >> 2) + 4 * kbase;
                atomicAdd(&sstat[ch * 2 + 0], s);
                atomicAdd(&sstat[ch * 2 + 1], q2);
            }
        }
    }

    // ---- stores: D col = px(ln31), row = oc offset (r&3)+8*(r>>2)+4*kbase
    #pragma unroll
    for (int mt = 0; mt < 2; ++mt) {
        const int pxb = p0 + wm * 64 + mt * 32;
        if (pxb < PIX) {
            const size_t pcol = (size_t)pxb + ln31;
            #pragma unroll
            for (int nt = 0; nt < 2; ++nt) {
                size_t obase = ((size_t)n * OO + wn * 64 + nt * 32 + kbase * 4) * PIX + pcol;
                #pragma unroll
                for (int r = 0; r < 16; ++r) {
                    int o_off = (r & 3) + 8 * (r >> 2);
                    if (MODE == 1) y16[obase + (size_t)o_off * PIX] = (short)acc[mt][nt][r];
                    else           out[obase + (size_t)o_off * PIX] = (float)acc[mt][nt][r];
                }
            }
        }
    }

    __syncthreads();
    // flush block stats: thread t -> stats[t] (ch = t>>1, metric = t&1)
    atomicAdd(&stats[tid], (unsigned long long)(long long)sstat[tid]);
}

__global__ void finalize_kernel(const unsigned long long* __restrict__ stats,
                                const float* __restrict__ gamma,
                                const float* __restrict__ beta,
                                float2* __restrict__ ss) {
    int c = threadIdx.x;
    if (c >= 128) return;
    long long s = (long long)stats[c * 2 + 0];
    long long q = (long long)stats[c * 2 + 1];
    double mean = (double)s / (double)CNT;
    double var = (double)q / (double)CNT - mean * mean;
    double inv = 1.0 / sqrt(var + 1e-5);
    double g = (double)gamma[c];
    float sc = (float)(g * inv);
    float sh = (float)((double)beta[c] - mean * g * inv);
    ss[c] = make_float2(sc, sh);
}

// 8 elements/thread; 3136 % 8 == 0 so a group never crosses a channel boundary.
__global__ void norm_kernel(const short* __restrict__ y16,
                            const float2* __restrict__ ss,
                            float* __restrict__ out) {
    size_t g = (size_t)blockIdx.x * 256 + threadIdx.x;
    size_t e = g * 8;
    unsigned int chan = (unsigned int)((e / PIX) & 127);
    float2 v = ss[chan];
    int4 raw = *reinterpret_cast<const int4*>(y16 + e);
    float4 o0, o1;
    o0.x = (float)(short)(raw.x & 0xffff) * v.x + v.y;
    o0.y = (float)(short)(raw.x >> 16)    * v.x + v.y;
    o0.z = (float)(short)(raw.y & 0xffff) * v.x + v.y;
    o0.w = (float)(short)(raw.y >> 16)    * v.x + v.y;
    o1.x = (float)(short)(raw.z & 0xffff) * v.x + v.y;
    o1.y = (float)(short)(raw.z >> 16)    * v.x + v.y;
    o1.z = (float)(short)(raw.w & 0xffff) * v.x + v.y;
    o1.w = (float)(short)(raw.w >> 16)    * v.x + v.y;
    *reinterpret_cast<float4*>(out + e) = o0;
    *reinterpret_cast<float4*>(out + e + 4) = o1;
}

// fallback: in-place normalize of raw float y in out
__global__ void normf_kernel(float* __restrict__ out, const float2* __restrict__ ss) {
    size_t g = (size_t)blockIdx.x * 256 + threadIdx.x;
    size_t e = g * 8;
    unsigned int chan = (unsigned int)((e / PIX) & 127);
    float2 v = ss[chan];
    float4 a = *reinterpret_cast<const float4*>(out + e);
    float4 b = *reinterpret_cast<const float4*>(out + e + 4);
    a.x = a.x * v.x + v.y; a.y = a.y * v.x + v.y; a.z = a.z * v.x + v.y; a.w = a.w * v.x + v.y;
    b.x = b.x * v.x + v.y; b.y = b.y * v.x + v.y; b.z = b.z * v.x + v.y; b.w = b.w * v.x + v.y;
    *reinterpret_cast<float4*>(out + e) = a;
    *reinterpret_cast<float4*>(out + e + 4) = b;
}

extern "C" void kernel_launch(void* const* d_in, const int* in_sizes, int n_in,
                              void* d_out, int out_size, void* d_ws, size_t ws_size,
                              hipStream_t stream) {
    const float* x     = (const float*)d_in[0];
    const float* wgt   = (const float*)d_in[1];
    const float* gamma = (const float*)d_in[2];
    const float* beta  = (const float*)d_in[3];
    float* out = (float*)d_out;
    char* ws = (char*)d_ws;

    char* wbt = ws + WS_WBT;
    unsigned long long* stats = (unsigned long long*)(ws + WS_STATS);
    float2* ssp = (float2*)(ws + WS_SS);
    char* xi8 = ws + WS_XI8;
    short* y16 = (short*)(ws + WS_Y16);

    hipMemsetAsync(stats, 0, 2048, stream);
    pack_w_i8<<<5, 256, 0, stream>>>(wgt, wbt);
    pack_x_i8<<<dim3(13, 64), 256, 0, stream>>>(x, xi8);

    if (ws_size >= WS_NEED) {
        conv_mfma<1><<<dim3(25, 64), 256, 0, stream>>>(xi8, wbt, stats, y16, nullptr);
        finalize_kernel<<<1, 128, 0, stream>>>(stats, gamma, beta, ssp);
        norm_kernel<<<(unsigned)(TOT / 8 / 256), 256, 0, stream>>>(y16, ssp, out);
    } else {
        conv_mfma<2><<<dim3(25, 64), 256, 0, stream>>>(xi8, wbt, stats, nullptr, out);
        finalize_kernel<<<1, 128, 0, stream>>>(stats, gamma, beta, ssp);
        normf_kernel<<<(unsigned)(TOT / 8 / 256), 256, 0, stream>>>(out, ssp);
    }
}

// Round 12
// 200.898 us; speedup vs baseline: 1.0370x; 1.0370x over previous
//
#include <hip/hip_runtime.h>
#include <stdint.h>

// BinConv2d: sign(x) conv3x3(pad1) sign(w) + batch-stat BN.
// Conv as int8 implicit GEMM on MFMA (v_mfma_i32_32x32x32_i8), integer-exact.
// R12 = R11 with the bw double-count bug fixed ((wn*64+ln31)*16 already holds wn*1024).

#define HH 56
#define WW 56
#define CC 128
#define OO 128
#define NIMG 64
#define PIX (HH*WW)               // 3136
#define CNT (NIMG*PIX)            // 200704 per channel
#define TOT ((size_t)NIMG*OO*PIX) // 25690112

#define APLANE 5584               // A-tile kc-plane stride in bytes (348*16 + 16 pad)

typedef int v4i  __attribute__((ext_vector_type(4)));
typedef int v16i __attribute__((ext_vector_type(16)));

// ws layout (bytes)
#define WS_WBT   0                 // 9*8*128*16 int8 (wbt2[tap][kc][o][16]) = 147456
#define WS_STATS 147456            // 128*{i64 sum, i64 sq} = 2048
#define WS_SS    149504            // float2[128] = 1024
#define WS_XI8   151552            // NHWC int8 sign(x): 64*3136*128 -> ends 25841664
#define WS_Y16   25841664          // TOT*int16 = 51380224 -> ends 77221888
#define WS_NEED  (25841664ULL + (size_t)TOT * 2)

// wbt2[tap][kc][o] x 16B: k-outer; B loads lane-consecutive 16B (coalesced)
__global__ void pack_w_i8(const float* __restrict__ w, char* __restrict__ wbt) {
    int t = blockIdx.x * 256 + threadIdx.x;
    if (t >= 1152) return;
    int tap = t >> 7, o = t & 127;
    const float* wp = w + (size_t)o * (CC * 9) + tap;   // OIHW: + c*9
    #pragma unroll
    for (int kc = 0; kc < 8; ++kc) {
        v4i v;
        #pragma unroll
        for (int wd = 0; wd < 4; ++wd) {
            unsigned u = 0;
            #pragma unroll
            for (int b = 0; b < 4; ++b) {
                int c = kc * 16 + wd * 4 + b;
                float f = wp[c * 9];
                int s = (f > 0.f) - (f < 0.f);
                u |= (unsigned)((unsigned char)(char)s) << (8 * b);
            }
            v[wd] = (int)u;
        }
        *(v4i*)(wbt + (((size_t)tap * 8 + kc) * 128 + o) * 16) = v;
    }
}

// xi8[n][h][w][c] int8 (NHWC, c contiguous = MFMA K dim)
__global__ void pack_x_i8(const float* __restrict__ x, char* __restrict__ xi8) {
    int n = blockIdx.y;
    int p = blockIdx.x * 256 + threadIdx.x;
    if (p >= PIX) return;
    const float* xp = x + (size_t)n * CC * PIX + p;
    char* dst = xi8 + ((size_t)n * PIX + p) * CC;
    #pragma unroll
    for (int chunk = 0; chunk < 8; ++chunk) {
        v4i v;
        #pragma unroll
        for (int wd = 0; wd < 4; ++wd) {
            unsigned u = 0;
            #pragma unroll
            for (int b = 0; b < 4; ++b) {
                int c = chunk * 16 + wd * 4 + b;
                float f = xp[(size_t)c * PIX];
                int s = (f > 0.f) - (f < 0.f);
                u |= (unsigned)((unsigned char)(char)s) << (8 * b);
            }
            v[wd] = (int)u;
        }
        *(v4i*)(dst + chunk * 16) = v;
    }
}

// MODE 1: y16 out. MODE 2: float y to out (fallback; normf in-place after).
// Block 256 = 4 waves (wm px-half, wn oc-half); block tile 128 px x 128 oc.
// Wave tile 64 px (2 mt) x 64 oc (2 nt); acc[2][2] = 64 regs.
template <int MODE>
__global__ __launch_bounds__(256, 3) void conv_mfma(
    const char* __restrict__ xi8, const char* __restrict__ wbt,
    unsigned long long* stats,
    short* __restrict__ y16, float* __restrict__ out)
{
    __shared__ __align__(16) char Atile[8 * APLANE];   // 44672
    __shared__ int sstat[256];

    const int strip = blockIdx.x;   // 0..24, 128 px each (last: 64 valid)
    const int n = blockIdx.y;
    const int tid = threadIdx.x;
    const int lane = tid & 63;
    const int wave = tid >> 6;
    const int wm = wave & 1;
    const int wn = wave >> 1;
    const int ln31 = lane & 31;
    const int kbase = lane >> 5;    // k half (0/1)
    const int p0 = strip * 128;
    const int r0 = p0 / 56 - 1;     // first tile image-row (may be -1)

    // ---- stage A, coalesced: idx -> p = idx>>3 (tile pixel 0..347), kc = idx&7.
    {
        const char* xim = xi8 + (size_t)n * PIX * CC;
        #pragma unroll
        for (int it = 0; it < 11; ++it) {
            int idx = tid + it * 256;
            if (idx < 8 * 348) {
                int p = idx >> 3, kc = idx & 7;
                int pr = p / 58, pc = p - pr * 58;
                int gr = r0 + pr, gw = pc - 1;
                v4i v = {0, 0, 0, 0};
                if (gr >= 0 && gr < HH && gw >= 0 && gw < WW)
                    v = *(const v4i*)(xim + ((size_t)(gr * WW + gw)) * CC + kc * 16);
                *(v4i*)(Atile + kc * APLANE + p * 16) = v;
            }
        }
        sstat[tid] = 0;
    }

    // per-mt activation base: pixel q = p0 + wm*64 + mt*32 + ln31
    int xpb[2];
    #pragma unroll
    for (int mt = 0; mt < 2; ++mt) {
        int q = p0 + wm * 64 + mt * 32 + ln31;
        int qr = q / 56;
        int hl0 = qr - (r0 + 1);               // tile row above pixel's row
        int wwp = q - qr * 56;
        xpb[mt] = (hl0 * 58 + wwp) * 16 + kbase * APLANE;   // + (dr*58+dc)*16 + ks*2*APLANE
    }
    // B base: wbt + tap*16384 + ks*4096 + kbase*2048 + o*16,
    // o*16 = (wn*64 + nt*32 + ln31)*16 = wn*1024 + nt*512 + ln31*16  (nt term added per load)
    const char* bw = wbt + kbase * 2048 + (wn * 64 + ln31) * 16;

    v16i acc[2][2];
    #pragma unroll
    for (int mt = 0; mt < 2; ++mt)
        #pragma unroll
        for (int nt = 0; nt < 2; ++nt)
            #pragma unroll
            for (int i = 0; i < 16; ++i) acc[mt][nt][i] = 0;

    // parity-indexed B reg double-buffer (indices compile-time after full unroll)
    v4i wf[2][2][4];
    #pragma unroll
    for (int nt = 0; nt < 2; ++nt)
        #pragma unroll
        for (int ks = 0; ks < 4; ++ks)
            wf[0][nt][ks] = *(const v4i*)(bw + ks * 4096 + nt * 512);

    __syncthreads();   // the only barrier

    #pragma unroll
    for (int tap = 0; tap < 9; ++tap) {
        const int cur = tap & 1, nxt = cur ^ 1;
        if (tap < 8) {
            #pragma unroll
            for (int nt = 0; nt < 2; ++nt)
                #pragma unroll
                for (int ks = 0; ks < 4; ++ks)
                    wf[nxt][nt][ks] = *(const v4i*)(bw + (tap + 1) * 16384 + ks * 4096 + nt * 512);
        }
        const int tapr = tap / 3, tapc = tap - tapr * 3;   // compile-time
        const int dtap = (tapr * 58 + tapc) * 16;
        v4i xf[2][4];
        #pragma unroll
        for (int mt = 0; mt < 2; ++mt)
            #pragma unroll
            for (int ks = 0; ks < 4; ++ks)
                xf[mt][ks] = *(const v4i*)(Atile + xpb[mt] + dtap + ks * 2 * APLANE);
        #pragma unroll
        for (int ks = 0; ks < 4; ++ks)
            #pragma unroll
            for (int mt = 0; mt < 2; ++mt)
                #pragma unroll
                for (int nt = 0; nt < 2; ++nt)
                    acc[mt][nt] = __builtin_amdgcn_mfma_i32_32x32x32_i8(
                        wf[cur][nt][ks], xf[mt][ks], acc[mt][nt], 0, 0, 0);
    }

    // ---- stats (validity-guarded; guards wave-uniform per mt since PIX % 32 == 0)
    const int pxb0 = p0 + wm * 64;
    const int pxb1 = pxb0 + 32;
    const bool v0 = pxb0 < PIX, v1 = pxb1 < PIX;
    #pragma unroll
    for (int nt = 0; nt < 2; ++nt) {
        #pragma unroll
        for (int r = 0; r < 16; ++r) {
            int a = v0 ? acc[0][nt][r] : 0;
            int b = v1 ? acc[1][nt][r] : 0;
            int s = a + b;
            int q2 = a * a + b * b;
            #pragma unroll
            for (int m = 1; m <= 16; m <<= 1) {
                s += __shfl_xor(s, m);
                q2 += __shfl_xor(q2, m);
            }
            if (ln31 == 0) {
                int ch = wn * 64 + nt * 32 + (r & 3) + 8 * (r >> 2) + 4 * kbase;
                atomicAdd(&sstat[ch * 2 + 0], s);
                atomicAdd(&sstat[ch * 2 + 1], q2);
            }
        }
    }

    // ---- stores: D col = px (ln31), row = oc offset (r&3)+8*(r>>2)+4*kbase
    #pragma unroll
    for (int mt = 0; mt < 2; ++mt) {
        const int pxb = p0 + wm * 64 + mt * 32;
        if (pxb < PIX) {
            const size_t pcol = (size_t)pxb + ln31;
            #pragma unroll
            for (int nt = 0; nt < 2; ++nt) {
                size_t obase = ((size_t)n * OO + wn * 64 + nt * 32 + kbase * 4) * PIX + pcol;
                #pragma unroll
                for (int r = 0; r < 16; ++r) {
                    int o_off = (r & 3) + 8 * (r >> 2);
                    if (MODE == 1) y16[obase + (size_t)o_off * PIX] = (short)acc[mt][nt][r];
                    else           out[obase + (size_t)o_off * PIX] = (float)acc[mt][nt][r];
                }
            }
        }
    }

    __syncthreads();
    atomicAdd(&stats[tid], (unsigned long long)(long long)sstat[tid]);
}

__global__ void finalize_kernel(const unsigned long long* __restrict__ stats,
                                const float* __restrict__ gamma,
                                const float* __restrict__ beta,
                                float2* __restrict__ ss) {
    int c = threadIdx.x;
    if (c >= 128) return;
    long long s = (long long)stats[c * 2 + 0];
    long long q = (long long)stats[c * 2 + 1];
    double mean = (double)s / (double)CNT;
    double var = (double)q / (double)CNT - mean * mean;
    double inv = 1.0 / sqrt(var + 1e-5);
    double g = (double)gamma[c];
    float sc = (float)(g * inv);
    float sh = (float)((double)beta[c] - mean * g * inv);
    ss[c] = make_float2(sc, sh);
}

// 8 elements/thread; 3136 % 8 == 0 so a group never crosses a channel boundary.
__global__ void norm_kernel(const short* __restrict__ y16,
                            const float2* __restrict__ ss,
                            float* __restrict__ out) {
    size_t g = (size_t)blockIdx.x * 256 + threadIdx.x;
    size_t e = g * 8;
    unsigned int chan = (unsigned int)((e / PIX) & 127);
    float2 v = ss[chan];
    int4 raw = *reinterpret_cast<const int4*>(y16 + e);
    float4 o0, o1;
    o0.x = (float)(short)(raw.x & 0xffff) * v.x + v.y;
    o0.y = (float)(short)(raw.x >> 16)    * v.x + v.y;
    o0.z = (float)(short)(raw.y & 0xffff) * v.x + v.y;
    o0.w = (float)(short)(raw.y >> 16)    * v.x + v.y;
    o1.x = (float)(short)(raw.z & 0xffff) * v.x + v.y;
    o1.y = (float)(short)(raw.z >> 16)    * v.x + v.y;
    o1.z = (float)(short)(raw.w & 0xffff) * v.x + v.y;
    o1.w = (float)(short)(raw.w >> 16)    * v.x + v.y;
    *reinterpret_cast<float4*>(out + e) = o0;
    *reinterpret_cast<float4*>(out + e + 4) = o1;
}

// fallback: in-place normalize of raw float y in out
__global__ void normf_kernel(float* __restrict__ out, const float2* __restrict__ ss) {
    size_t g = (size_t)blockIdx.x * 256 + threadIdx.x;
    size_t e = g * 8;
    unsigned int chan = (unsigned int)((e / PIX) & 127);
    float2 v = ss[chan];
    float4 a = *reinterpret_cast<const float4*>(out + e);
    float4 b = *reinterpret_cast<const float4*>(out + e + 4);
    a.x = a.x * v.x + v.y; a.y = a.y * v.x + v.y; a.z = a.z * v.x + v.y; a.w = a.w * v.x + v.y;
    b.x = b.x * v.x + v.y; b.y = b.y * v.x + v.y; b.z = b.z * v.x + v.y; b.w = b.w * v.x + v.y;
    *reinterpret_cast<float4*>(out + e) = a;
    *reinterpret_cast<float4*>(out + e + 4) = b;
}

extern "C" void kernel_launch(void* const* d_in, const int* in_sizes, int n_in,
                              void* d_out, int out_size, void* d_ws, size_t ws_size,
                              hipStream_t stream) {
    const float* x     = (const float*)d_in[0];
    const float* wgt   = (const float*)d_in[1];
    const float* gamma = (const float*)d_in[2];
    const float* beta  = (const float*)d_in[3];
    float* out = (float*)d_out;
    char* ws = (char*)d_ws;

    char* wbt = ws + WS_WBT;
    unsigned long long* stats = (unsigned long long*)(ws + WS_STATS);
    float2* ssp = (float2*)(ws + WS_SS);
    char* xi8 = ws + WS_XI8;
    short* y16 = (short*)(ws + WS_Y16);

    hipMemsetAsync(stats, 0, 2048, stream);
    pack_w_i8<<<5, 256, 0, stream>>>(wgt, wbt);
    pack_x_i8<<<dim3(13, 64), 256, 0, stream>>>(x, xi8);

    if (ws_size >= WS_NEED) {
        conv_mfma<1><<<dim3(25, 64), 256, 0, stream>>>(xi8, wbt, stats, y16, nullptr);
        finalize_kernel<<<1, 128, 0, stream>>>(stats, gamma, beta, ssp);
        norm_kernel<<<(unsigned)(TOT / 8 / 256), 256, 0, stream>>>(y16, ssp, out);
    } else {
        conv_mfma<2><<<dim3(25, 64), 256, 0, stream>>>(xi8, wbt, stats, nullptr, out);
        finalize_kernel<<<1, 128, 0, stream>>>(stats, gamma, beta, ssp);
        normf_kernel<<<(unsigned)(TOT / 8 / 256), 256, 0, stream>>>(out, ssp);
    }
}